// Round 5
// baseline (139.449 us; speedup 1.0000x reference)
//
#include <hip/hip_runtime.h>
#include <hip/hip_cooperative_groups.h>

namespace cg = cooperative_groups;

#define NN 4096
#define FIN 128
#define NHEAD 4
#define NHID 16
#define NCOL 64
#define SLOPE 0.2f
#define CHUNK 64
#define NCH 64      // NN / CHUNK
#define NCOLS 17    // 16 value cols + denominator col

__device__ __forceinline__ float lrelu(float v){ return v > 0.f ? v : SLOPE * v; }

// One LDS arena, reused phase-by-phase (max member ~44 KB -> 1 block/CU fits easily).
union Smem {
  struct { float wl[FIN][NCOL]; float xl[16][FIN]; float hs[16][NCOL + 1]; } g; // 45 KB
  struct { unsigned long long keys[NN]; int rsum[64][4]; } r;                   // 33.8 KB
  struct { float e02[CHUNK]; float e1[CHUNK];
           float hl[CHUNK][NCOLS]; float PLs[CHUNK][NCOLS]; float SLs[CHUNK][NCOLS]; } a; // 13.6 KB
  struct { float oP[NCH + 1][68]; float oS[NCH][68]; } o;                       // 35.1 KB
};

__global__ __launch_bounds__(256, 1) void fused_k(
    const float* __restrict__ x, const float* __restrict__ W,
    const float* __restrict__ aw,
    float* __restrict__ h, float* __restrict__ src, float* __restrict__ dst,
    float* __restrict__ dsort, int* __restrict__ perm,
    float* __restrict__ PL, float* __restrict__ SL,
    float* __restrict__ ctP, float* __restrict__ ctS,
    float* __restrict__ out)
{
  __shared__ Smem sm;
  cg::grid_group grid = cg::this_grid();
  const int b = blockIdx.x;   // exactly 256 blocks
  const int t = threadIdx.x;

  // ================= Phase 1: h = x@W (+ fused src/dst epilogue) =================
  {
    for (int k = t; k < FIN * NCOL; k += 256) sm.g.wl[k >> 6][k & 63] = W[k];
    int row0 = b * 16;
    for (int k = t; k < 16 * FIN; k += 256) sm.g.xl[k >> 7][k & 127] = x[row0 * FIN + k];
    __syncthreads();
    int col = t & 63, rb = t >> 6;
    float acc[4] = {0.f, 0.f, 0.f, 0.f};
    #pragma unroll
    for (int d = 0; d < FIN; ++d){
      float wv = sm.g.wl[d][col];            // stride-1 across lanes: conflict-free
      #pragma unroll
      for (int rr = 0; rr < 4; ++rr)         // xl read is wave-uniform: broadcast
        acc[rr] = fmaf(sm.g.xl[rb * 4 + rr][d], wv, acc[rr]);
    }
    #pragma unroll
    for (int rr = 0; rr < 4; ++rr){
      int r = rb * 4 + rr;
      h[(row0 + r) * NCOL + col] = acc[rr];
      sm.g.hs[r][col] = acc[rr];
    }
    __syncthreads();
    if (t < 64){
      int r = t >> 2, hd = t & 3;
      float s = 0.f, d = 0.f;
      #pragma unroll
      for (int f = 0; f < NHID; ++f){
        float v = sm.g.hs[r][hd * NHID + f];
        s = fmaf(v, aw[f], s);
        d = fmaf(v, aw[NHID + f], d);
      }
      src[hd * NN + row0 + r] = s;
      dst[hd * NN + row0 + r] = d;
    }
  }
  grid.sync();

  // ================= Phase 2: rank-by-counting + scatter (block-complete) =======
  {
    int hd = b >> 6, ib = b & 63;           // 4 heads x 64 i-blocks
    const float* dp = dst + hd * NN;
    for (int k = t; k < NN; k += 256){
      unsigned int bb = __float_as_uint(dp[k]);
      bb ^= (bb & 0x80000000u) ? 0xFFFFFFFFu : 0x80000000u;  // float -> sortable uint
      sm.r.keys[k] = ((unsigned long long)bb << 32) | (unsigned int)k;
    }
    __syncthreads();
    int w = t >> 6, l = t & 63;             // wave w handles j-quarter w; lane = i
    int i = ib * 64 + l;
    unsigned long long my = sm.r.keys[i];
    int j0 = w * 1024;
    int cnt = 0;
    #pragma unroll 8
    for (int kk = 0; kk < 1024; ++kk)       // wave-uniform LDS read: broadcast
      cnt += (sm.r.keys[j0 + kk] < my) ? 1 : 0;
    sm.r.rsum[l][w] = cnt;
    __syncthreads();
    if (t < 64){
      int ii = ib * 64 + t;
      int rk = sm.r.rsum[t][0] + sm.r.rsum[t][1] + sm.r.rsum[t][2] + sm.r.rsum[t][3];
      dsort[hd * NN + rk] = dp[ii];
      perm[hd * NN + rk]  = ii;
    }
  }
  grid.sync();

  // ================= Phase 3: per-(head,chunk) local prefix/suffix scans ========
  {
    int hd = b >> 6, ch = b & 63;
    int base = ch * CHUNK;
    const float* ds = dsort + hd * NN;
    const int*   pm = perm + hd * NN;
    if (t < CHUNK){
      float d = ds[base + t];
      sm.a.e02[t] = __expf(0.2f * d);
      sm.a.e1[t]  = __expf(d);
      sm.a.hl[t][16] = 1.0f;
    }
    {
      int col = t & 15, r0 = t >> 4;
      #pragma unroll
      for (int it = 0; it < 4; ++it){
        int r = it * 16 + r0;
        sm.a.hl[r][col] = h[pm[base + r] * NCOL + hd * NHID + col];
      }
    }
    __syncthreads();
    if (t < NCOLS){
      int col = t;
      float run = 0.f;
      #pragma unroll
      for (int r = 0; r < CHUNK; ++r){
        sm.a.PLs[r][col] = run;
        run = fmaf(sm.a.e02[r], sm.a.hl[r][col], run);
      }
      ctP[ch * 68 + hd * 17 + col] = run;
    } else if (t >= 64 && t < 64 + NCOLS){
      int col = t - 64;
      float rs = 0.f;
      #pragma unroll
      for (int r = CHUNK - 1; r >= 0; --r){
        rs = fmaf(sm.a.e1[r], sm.a.hl[r][col], rs);
        sm.a.SLs[r][col] = rs;
      }
      ctS[ch * 68 + hd * 17 + col] = rs;
    }
    __syncthreads();
    for (int idx = t; idx < NCOLS * CHUNK; idx += 256){
      int col = idx >> 6, r = idx & 63;
      PL[(hd * 17 + col) * NN + base + r] = sm.a.PLs[r][col];
      SL[(hd * 17 + col) * NN + base + r] = sm.a.SLs[r][col];
    }
  }
  grid.sync();

  // ===== Phase 4: scan chunk totals, replicated per block, LDS-resident =========
  {
    float* oPf = &sm.o.oP[0][0];
    float* oSf = &sm.o.oS[0][0];
    for (int idx = t; idx < NCH * 68; idx += 256){
      oPf[idx] = ctP[idx];
      oSf[idx] = ctS[idx];
    }
    __syncthreads();
    if (t < 68){
      float v[NCH];
      #pragma unroll
      for (int c = 0; c < NCH; ++c) v[c] = sm.o.oP[c][t];
      float run = 0.f;
      #pragma unroll
      for (int c = 0; c < NCH; ++c){ sm.o.oP[c][t] = run; run += v[c]; }
      sm.o.oP[NCH][t] = run;                 // grand totals (for k==NN case)
    } else if (t >= 128 && t < 196){
      int col = t - 128;
      float v[NCH];
      #pragma unroll
      for (int c = 0; c < NCH; ++c) v[c] = sm.o.oS[c][col];
      float rs = 0.f;
      #pragma unroll
      for (int c = NCH - 1; c >= 0; --c){ sm.o.oS[c][col] = rs; rs += v[c]; }
    }
    __syncthreads();
  }

  // ================= Phase 5: binary-search kink + two-level combine ============
  {
    int pr = t >> 2, fq = t & 3;             // 4 threads per (i,head) pair
    int p = b * 64 + pr;                     // 256 blocks x 64 pairs = 16384
    int i = p >> 2, hd = p & 3;
    float s = src[hd * NN + i];
    const float* ds = dsort + hd * NN;
    float tthr = -s;
    int lo = 0, hi = NN;
    while (lo < hi){
      int mid = (lo + hi) >> 1;
      if (ds[mid] < tthr) lo = mid + 1; else hi = mid;
    }
    int k = lo;                              // ranks < k take the 0.2 branch
    float m = lrelu(s + ds[NN - 1]);
    float alpha = __expf(0.2f * s - m);
    float beta  = __expf(s - m);
    float* op = out + i * NCOL + hd * NHID;
    if (k == NN){                            // everything in 0.2 branch: alpha cancels
      float inv = 1.0f / sm.o.oP[NCH][hd * 17 + 16];
      #pragma unroll
      for (int ff = 0; ff < 4; ++ff){
        int f = fq * 4 + ff;
        op[f] = sm.o.oP[NCH][hd * 17 + f] * inv;
      }
    } else {
      int ch = k >> 6;
      const float* PLp = PL + (hd * 17) * NN + k;
      const float* SLp = SL + (hd * 17) * NN + k;
      float den = alpha * (PLp[16 * NN] + sm.o.oP[ch][hd * 17 + 16])
                + beta  * (SLp[16 * NN] + sm.o.oS[ch][hd * 17 + 16]);
      float inv = 1.0f / den;
      #pragma unroll
      for (int ff = 0; ff < 4; ++ff){
        int f = fq * 4 + ff;
        float num = alpha * (PLp[f * NN] + sm.o.oP[ch][hd * 17 + f])
                  + beta  * (SLp[f * NN] + sm.o.oS[ch][hd * 17 + f]);
        op[f] = num * inv;
      }
    }
  }
}

extern "C" void kernel_launch(void* const* d_in, const int* in_sizes, int n_in,
                              void* d_out, int out_size, void* d_ws, size_t ws_size,
                              hipStream_t stream){
  const float* x  = (const float*)d_in[0];
  // d_in[1] = adj : UNUSED by the reference (no masking) — never read it.
  const float* W  = (const float*)d_in[2];
  const float* aw = (const float*)d_in[3];
  float* out = (float*)d_out;
  float* ws  = (float*)d_ws;

  float* h     = ws;                  // 262144
  float* src   = ws + 262144;         // 16384
  float* dst   = ws + 278528;         // 16384
  float* dsort = ws + 294912;         // 16384
  int*   perm  = (int*)(ws + 311296); // 16384
  float* PL    = ws + 327680;         // 278528
  float* SL    = ws + 606208;         // 278528
  float* ctP   = ws + 884736;         // 4352
  float* ctS   = ws + 889088;         // 4352
  // total ~3.58 MB

  void* args[] = {(void*)&x, (void*)&W, (void*)&aw, (void*)&h, (void*)&src,
                  (void*)&dst, (void*)&dsort, (void*)&perm, (void*)&PL,
                  (void*)&SL, (void*)&ctP, (void*)&ctS, (void*)&out};
  hipLaunchCooperativeKernel((void*)fused_k, dim3(256), dim3(256), args, 0, stream);
}

// Round 6
// 40.086 us; speedup vs baseline: 3.4787x; 3.4787x over previous
//
#include <hip/hip_runtime.h>

#define NN 4096
#define FIN 128
#define NHEAD 4
#define NHID 16
#define NCOL 64
#define SLOPE 0.2f
#define CHUNK 64
#define NCH 64      // NN / CHUNK
#define NCOLS 17    // 16 value cols + denominator col

__device__ __forceinline__ float lrelu(float v){ return v > 0.f ? v : SLOPE * v; }

// K1: h = x@W (+ src/dst epilogue). 512 blocks x 8 rows -> 2 blocks/CU.
__global__ __launch_bounds__(256) void gemm_h_k(const float* __restrict__ x,
                                                const float* __restrict__ W,
                                                const float* __restrict__ aw,
                                                float* __restrict__ h,
                                                float* __restrict__ src,
                                                float* __restrict__ dst){
  __shared__ float wl[FIN][NCOL];    // 32 KB
  __shared__ float xl[8][FIN];       // 4 KB
  __shared__ float hs[8][NCOL + 1];  // 2 KB
  int t = threadIdx.x;
  int row0 = blockIdx.x * 8;
  for (int k = t; k < FIN * NCOL; k += 256) wl[k >> 6][k & 63] = W[k];
  for (int k = t; k < 8 * FIN; k += 256) xl[k >> 7][k & 127] = x[row0 * FIN + k];
  __syncthreads();
  int col = t & 63, rb = t >> 6;     // rb wave-uniform -> xl reads broadcast
  float a0 = 0.f, a1 = 0.f;
  #pragma unroll
  for (int d = 0; d < FIN; ++d){
    float wv = wl[d][col];           // 2-way bank alias across 64 lanes: free
    a0 = fmaf(xl[rb * 2][d],     wv, a0);
    a1 = fmaf(xl[rb * 2 + 1][d], wv, a1);
  }
  h[(row0 + rb * 2) * NCOL + col] = a0;     hs[rb * 2][col] = a0;
  h[(row0 + rb * 2 + 1) * NCOL + col] = a1; hs[rb * 2 + 1][col] = a1;
  __syncthreads();
  if (t < 32){
    int r = t >> 2, hd = t & 3;
    float s = 0.f, d = 0.f;
    #pragma unroll
    for (int f = 0; f < NHID; ++f){
      float v = hs[r][hd * NHID + f];
      s = fmaf(v, aw[f], s);
      d = fmaf(v, aw[NHID + f], d);
    }
    src[hd * NN + row0 + r] = s;
    dst[hd * NN + row0 + r] = d;
  }
}

// K2: block-complete rank-by-counting + scatter. 512 blocks (128 i-blk x 4 heads).
// Keys staged in 8 padded segments of 513 -> the 8 parallel j-segments land on
// distinct banks; 8-way address replication across the wave is broadcast.
__global__ __launch_bounds__(256) void ranksc_k(const float* __restrict__ dst,
                                                float* __restrict__ dsort,
                                                int* __restrict__ perm){
  int ib = blockIdx.x;   // 0..127 -> 32 i's each
  int hd = blockIdx.y;   // 0..3
  __shared__ unsigned long long keys[8 * 513];   // 32.8 KB
  int t = threadIdx.x;
  const float* dp = dst + hd * NN;
  for (int j = t; j < NN; j += 256){
    unsigned int b = __float_as_uint(dp[j]);
    b ^= (b & 0x80000000u) ? 0xFFFFFFFFu : 0x80000000u;  // float -> sortable uint
    keys[(j >> 9) * 513 + (j & 511)] = ((unsigned long long)b << 32) | (unsigned int)j;
  }
  __syncthreads();
  int il = t >> 3, jseg = t & 7;
  int i = ib * 32 + il;
  unsigned long long my = keys[(i >> 9) * 513 + (i & 511)];
  const unsigned long long* kp = &keys[jseg * 513];
  int cnt = 0;
  #pragma unroll 8
  for (int kk = 0; kk < 512; ++kk) cnt += (kp[kk] < my) ? 1 : 0;
  cnt += __shfl_down(cnt, 4);    // 8-lane groups are wave-contiguous
  cnt += __shfl_down(cnt, 2);
  cnt += __shfl_down(cnt, 1);
  if (jseg == 0){
    dsort[hd * NN + cnt] = dp[i];
    perm[hd * NN + cnt]  = i;
  }
}

// K3: per-(head,chunk) local prefix/suffix scans. 256 blocks.
__global__ __launch_bounds__(256) void scanA_k(const float* __restrict__ h,
                                               const float* __restrict__ dsort,
                                               const int* __restrict__ perm,
                                               float* __restrict__ PL,
                                               float* __restrict__ SL,
                                               float* __restrict__ ctP,
                                               float* __restrict__ ctS){
  int ch = blockIdx.x;   // 64
  int hd = blockIdx.y;   // 4
  int t = threadIdx.x;
  int base = ch * CHUNK;
  __shared__ float e02[CHUNK], e1[CHUNK];
  __shared__ float hl[CHUNK][NCOLS];
  __shared__ float PLs[CHUNK][NCOLS], SLs[CHUNK][NCOLS];
  const float* ds = dsort + hd * NN;
  const int*   pm = perm + hd * NN;
  if (t < CHUNK){
    float d = ds[base + t];
    e02[t] = __expf(0.2f * d);
    e1[t]  = __expf(d);
    hl[t][16] = 1.0f;
  }
  {
    int col = t & 15, r0 = t >> 4;
    #pragma unroll
    for (int it = 0; it < 4; ++it){
      int r = it * 16 + r0;
      hl[r][col] = h[pm[base + r] * NCOL + hd * NHID + col];
    }
  }
  __syncthreads();
  if (t < NCOLS){
    int col = t;
    float run = 0.f;
    #pragma unroll
    for (int r = 0; r < CHUNK; ++r){
      PLs[r][col] = run;
      run = fmaf(e02[r], hl[r][col], run);
    }
    ctP[ch * 68 + hd * 17 + col] = run;
  } else if (t >= 64 && t < 64 + NCOLS){
    int col = t - 64;
    float rs = 0.f;
    #pragma unroll
    for (int r = CHUNK - 1; r >= 0; --r){
      rs = fmaf(e1[r], hl[r][col], rs);
      SLs[r][col] = rs;
    }
    ctS[ch * 68 + hd * 17 + col] = rs;
  }
  __syncthreads();
  for (int idx = t; idx < NCOLS * CHUNK; idx += 256){
    int col = idx >> 6, r = idx & 63;
    PL[(hd * 17 + col) * NN + base + r] = PLs[r][col];
    SL[(hd * 17 + col) * NN + base + r] = SLs[r][col];
  }
}

// K4: per-block LDS scan of chunk totals + binary-search kink + combine.
// 512 blocks x 32 pairs, 8 threads per (i,head) pair.
__global__ __launch_bounds__(256) void out_k(const float* __restrict__ src,
                                             const float* __restrict__ dsort,
                                             const float* __restrict__ PL,
                                             const float* __restrict__ SL,
                                             const float* __restrict__ ctP,
                                             const float* __restrict__ ctS,
                                             float* __restrict__ out){
  __shared__ float oP[NCH + 1][68];   // 17.7 KB (row NCH = grand totals)
  __shared__ float oS[NCH][68];       // 17.4 KB
  int t = threadIdx.x;
  for (int idx = t; idx < NCH * 68; idx += 256){
    (&oP[0][0])[idx] = ctP[idx];
    (&oS[0][0])[idx] = ctS[idx];
  }
  __syncthreads();
  if (t < 68){
    float run = 0.f;
    #pragma unroll
    for (int c = 0; c < NCH; ++c){ float v = oP[c][t]; oP[c][t] = run; run += v; }
    oP[NCH][t] = run;
  } else if (t >= 128 && t < 196){
    int cc = t - 128;
    float rs = 0.f;
    #pragma unroll
    for (int c = NCH - 1; c >= 0; --c){ float v = oS[c][cc]; oS[c][cc] = rs; rs += v; }
  }
  __syncthreads();
  int tg = t >> 3, q = t & 7;
  int p = blockIdx.x * 32 + tg;        // 512*32 = 16384 pairs
  int i = p >> 2, hd = p & 3;
  float s = src[hd * NN + i];
  const float* ds = dsort + hd * NN;
  float tthr = -s;
  int lo = 0, hi = NN;
  while (lo < hi){
    int mid = (lo + hi) >> 1;
    if (ds[mid] < tthr) lo = mid + 1; else hi = mid;
  }
  int k = lo;                          // ranks < k take the 0.2 branch
  float* op = out + i * NCOL + hd * NHID;
  if (k == NN){                        // all in 0.2 branch: alpha cancels
    float inv = 1.0f / oP[NCH][hd * 17 + 16];
    int f0 = q * 2;
    op[f0]     = oP[NCH][hd * 17 + f0] * inv;
    op[f0 + 1] = oP[NCH][hd * 17 + f0 + 1] * inv;
  } else {
    float m = lrelu(s + ds[NN - 1]);
    float alpha = __expf(0.2f * s - m);
    float beta  = __expf(s - m);
    int ch = k >> 6;
    const float* PLp = PL + (hd * 17) * NN + k;
    const float* SLp = SL + (hd * 17) * NN + k;
    float den = alpha * (PLp[16 * NN] + oP[ch][hd * 17 + 16])
              + beta  * (SLp[16 * NN] + oS[ch][hd * 17 + 16]);
    float inv = 1.0f / den;
    #pragma unroll
    for (int ff = 0; ff < 2; ++ff){
      int f = q * 2 + ff;
      float num = alpha * (PLp[f * NN] + oP[ch][hd * 17 + f])
                + beta  * (SLp[f * NN] + oS[ch][hd * 17 + f]);
      op[f] = num * inv;
    }
  }
}

extern "C" void kernel_launch(void* const* d_in, const int* in_sizes, int n_in,
                              void* d_out, int out_size, void* d_ws, size_t ws_size,
                              hipStream_t stream){
  const float* x  = (const float*)d_in[0];
  // d_in[1] = adj : UNUSED by the reference (no masking) — never read it.
  const float* W  = (const float*)d_in[2];
  const float* aw = (const float*)d_in[3];
  float* out = (float*)d_out;
  float* ws  = (float*)d_ws;

  float* h     = ws;                  // 262144
  float* src   = ws + 262144;         // 16384
  float* dst   = ws + 278528;         // 16384
  float* dsort = ws + 294912;         // 16384
  int*   perm  = (int*)(ws + 311296); // 16384
  float* PL    = ws + 327680;         // 278528
  float* SL    = ws + 606208;         // 278528
  float* ctP   = ws + 884736;         // 4352
  float* ctS   = ws + 889088;         // 4352
  // total ~3.58 MB

  gemm_h_k<<<512, 256, 0, stream>>>(x, W, aw, h, src, dst);
  ranksc_k<<<dim3(128, NHEAD), 256, 0, stream>>>(dst, dsort, perm);
  scanA_k<<<dim3(NCH, NHEAD), 256, 0, stream>>>(h, dsort, perm, PL, SL, ctP, ctS);
  out_k<<<512, 256, 0, stream>>>(src, dsort, PL, SL, ctP, ctS, out);
}